// Round 11
// baseline (168.420 us; speedup 1.0000x reference)
//
#include <hip/hip_runtime.h>
#include <hip/hip_bf16.h>

// B=4, C=64, H=W=64, D=4, CQ=8. N=H*W=4096, f_qk=32, f_v=256. I/O fp32.
// R21 = R19 (flash 57.4us best) + Va REGISTER PREFETCH, minus R20's sleep
// (measured neutral -> removed). R20 falsified the block-lockstep theory;
// remaining idle ~34% is within-wave dependency stalls. The one still-
// exposed latency: PV's 8 ds_read_b128 (~120cy) only partially covered by
// 4-MFMA groups (~78cy) -> ~300-400cy/pt exposed. Fix: issue all 8 reads
// into Va[8] regs right after the barrier (buffer just validated); they
// complete under DMA-issue + K-issue + exp + QK(pt+1) (~1500cy) and PV
// becomes a pure register MFMA burst. +64 VGPR (~192 total, <256 cap of
// launch_bounds(256,2)); static indexing keeps Va in regs (rule #20).
// R19 carried: pipeline rotation (exp(pt) || QK(pt+1) -> PV(pt)), R12 V
// staging/barrier structure, XCD affinity (FETCH 31.8->14.9MB verified),
// log2e-in-Q + asm v_exp_f32, setprio. qkv UNCHANGED.
#define CH 64
#define NN 4096
#define SS 16384

typedef __attribute__((ext_vector_type(8))) short bf16x8;
typedef __attribute__((ext_vector_type(4))) float f32x4;

// ws layout (ushort elems): Qb (B,N,32) | Kb (B,N,32) |
// Vt [b][sup:32][cv:256][slot:144] (128 data slots + 16 pad)
#define QB_OFF 0
#define KB_OFF 524288
#define VT_OFF 1048576

static __device__ __forceinline__ ushort bfbits(float x) {
    __hip_bfloat16 h = __float2bfloat16(x);
    return *(ushort*)&h;
}

// 2^x in one HW instruction (trans pipe).
static __device__ __forceinline__ float fexp2(float x) {
    float r;
    asm("v_exp_f32 %0, %1" : "=v"(r) : "v"(x));
    return r;
}

static __device__ __forceinline__ void gld_lds16(const ushort* g, ushort* l) {
    __builtin_amdgcn_global_load_lds(
        (const __attribute__((address_space(1))) void*)g,
        (__attribute__((address_space(3))) void*)l, 16, 0, 0);
}

// ---------------- qkv ---------------- (unchanged)
// grid 512. XCD-affine decode: xcd = blk&7 owns batch xcd>>1; the 4 og
// blocks of one (b,sup) share an XCD so the 128KB x-slab is fetched into
// one L2 once. 256 threads = (nl = tid>>2, d).
// og0: q8 + v[0:12); og1: k8 + v[12:24); og2: v[24:44); og3: v[44:64).
__global__ __launch_bounds__(256) void qkv_kernel(
    const float* __restrict__ x,
    const float* __restrict__ Wq, const float* __restrict__ bq,
    const float* __restrict__ Wk, const float* __restrict__ bk,
    const float* __restrict__ Wv, const float* __restrict__ bv,
    ushort* __restrict__ qb, ushort* __restrict__ kb, ushort* __restrict__ vt)
{
    __shared__ __align__(16) ushort Tqk[128 * 40];  // [n_loc][f], q or k
    __shared__ __align__(16) ushort Tv[80 * 144];   // [cv_loc][slot]

    const int blk = blockIdx.x;
    const int xcd = blk & 7, jb = blk >> 3;          // jb in [0,64)
    const int b = xcd >> 1;
    const int sup = ((xcd & 1) << 4) | (jb & 15);
    const int og = jb >> 4;
    const int tid = threadIdx.x;
    const int nl = tid >> 2, d = tid & 3;

    const int vcnt = (og < 2) ? 12 : 20;
    const int vo0 = (og == 0) ? 0 : (og == 1) ? 12 : (og == 2) ? 24 : 44;

    // fold log2(e) into q so flash computes exp(s) as 2^s (v_exp_f32 direct)
    const float qscale = (og == 0) ? 1.4426950408889634f : 1.0f;

    const float* xb = x + (size_t)b * CH * SS + sup * 512;

    for (int t = 0; t < 2; ++t) {
        const float* xp = xb + t * 256 + tid;
        float xr[CH];
#pragma unroll
        for (int c = 0; c < CH; ++c) xr[c] = xp[(size_t)c * SS];

        // flash pair-interleave: m_loc = nl of tile t -> slot
        const int slot = 32 * (nl >> 4) + 8 * ((nl >> 2) & 3) + 4 * t + (nl & 3);

        if (og < 2) {
            const float* Wqk = (og == 0) ? Wq : Wk;
            const float* bqk = (og == 0) ? bq : bk;
            ushort* trow = &Tqk[(t * 64 + nl) * 40 + d];
#pragma unroll
            for (int o = 0; o < 8; o += 2) {
                float a0 = bqk[o], a1 = bqk[o + 1];
#pragma unroll
                for (int c = 0; c < CH; ++c) {
                    a0 = fmaf(Wqk[o * CH + c],       xr[c], a0);
                    a1 = fmaf(Wqk[(o + 1) * CH + c], xr[c], a1);
                }
                trow[o * 4]       = bfbits(a0 * qscale);
                trow[(o + 1) * 4] = bfbits(a1 * qscale);
            }
        }
        ushort* vcol = &Tv[d * 144 + slot];
        const float* Wvb = Wv + vo0 * CH;
        const float* bvb = bv + vo0;
        if (og < 2) {
#pragma unroll
            for (int j = 0; j < 12; j += 2) {
                float a0 = bvb[j], a1 = bvb[j + 1];
#pragma unroll
                for (int c = 0; c < CH; ++c) {
                    a0 = fmaf(Wvb[j * CH + c],       xr[c], a0);
                    a1 = fmaf(Wvb[(j + 1) * CH + c], xr[c], a1);
                }
                vcol[(j * 4) * 144]       = bfbits(a0);
                vcol[((j + 1) * 4) * 144] = bfbits(a1);
            }
        } else {
#pragma unroll
            for (int j = 0; j < 20; j += 2) {
                float a0 = bvb[j], a1 = bvb[j + 1];
#pragma unroll
                for (int c = 0; c < CH; ++c) {
                    a0 = fmaf(Wvb[j * CH + c],       xr[c], a0);
                    a1 = fmaf(Wvb[(j + 1) * CH + c], xr[c], a1);
                }
                vcol[(j * 4) * 144]       = bfbits(a0);
                vcol[((j + 1) * 4) * 144] = bfbits(a1);
            }
        }
    }
    __syncthreads();

    // Q/K readout: 128 rows x 32 ushorts = 512 uint4 chunks, 2 per thread
    if (og < 2) {
        ushort* dst = (og == 0 ? qb : kb);
#pragma unroll
        for (int jj = 0; jj < 2; ++jj) {
            int idx = jj * 256 + tid;
            int row = idx >> 2, seg = idx & 3;
            *(uint4*)(dst + ((size_t)(b * NN + sup * 128 + row)) * 32 + seg * 8)
                = *(const uint4*)&Tqk[row * 40 + seg * 8];
        }
    }
    // V readout: vcnt*4 rows x 128 data slots = vcnt*64 uint4 chunks
    const int nchunks = vcnt * 64;   // 768 (og<2) or 1280 (og>=2)
    ushort* vout = vt + ((size_t)((b * 32 + sup) * 256 + vo0 * 4)) * 144;
#pragma unroll
    for (int j = 0; j < 5; ++j) {
        int idx = j * 256 + tid;
        if (idx < nchunks) {
            int row = idx >> 4, seg = idx & 15;
            *(uint4*)(vout + (size_t)row * 144 + seg * 8)
                = *(const uint4*)&Tv[row * 144 + seg * 8];
        }
    }
}

// ---------------- flash ----------------
// grid 512. XCD-affine decode: xcd = blk&7 -> batch xcd>>1, cv-half xcd&1,
// r-tile = blk>>3. 256 threads = 4 waves; wave w owns m-slice [16w,16w+16)
// of each 64-m tile; pair pt = 2 tiles = 32 k. V staged async global->LDS,
// double-buffered, one barrier per pt. Pipeline rotation: iter pt does
// Va-prefetch(pt), exp(pt), QK(pt+1), PV(pt); S and Ka persist across iters.
__global__ __launch_bounds__(256, 2) void flash_kernel(
    const ushort* __restrict__ qb, const ushort* __restrict__ kb,
    const ushort* __restrict__ vt, const float* __restrict__ x3d,
    const float* __restrict__ gptr, float* __restrict__ out)
{
    __shared__ __align__(16) ushort Vls[2][128 * 144];  // [cv'][slot], dbuf
    __shared__ float lbuf[4 * 4 * 16];

    const int tid = threadIdx.x;
    const int xcd = blockIdx.x & 7, jb = blockIdx.x >> 3;  // jb in [0,64)
    const int b   = xcd >> 1;
    const int r0  = (jb & 63) << 6;
    const int cvh = xcd & 1;
    const int w = tid >> 6, lane = tid & 63, q = lane >> 4, l15 = lane & 15;

    // Q B-frags (16x16x32): B[f=8q+j][r=16rt+l15]
    bf16x8 Qf[4];
#pragma unroll
    for (int rt = 0; rt < 4; ++rt)
        Qf[rt] = *(const bf16x8*)(qb + (size_t)(b * NN + r0 + 16 * rt + l15) * 32 + 8 * q);

    f32x4 acc[8][4];
#pragma unroll
    for (int i = 0; i < 8; ++i)
#pragma unroll
        for (int j = 0; j < 4; ++j) acc[i][j] = (f32x4){0.f, 0.f, 0.f, 0.f};
    float l_acc[4] = {0.f, 0.f, 0.f, 0.f};

    // K rows for wave w, tile mt: kb[(mt*64 + 16w + l15)*32 + 8q]
    const ushort* kgl = kb + (size_t)b * NN * 32 + (16 * w + l15) * 32 + 8 * q;

    // V stream: block's 128-cv half of each sup = 128*144 ushorts contiguous
    const ushort* vgl = vt + ((size_t)(b * 32) * 256 + 128 * cvh) * 144;

    // async stage pair 0 -> buf 0 (wave-uniform base + lane*16: valid DMA)
#pragma unroll
    for (int i = 0; i < 9; ++i)
        gld_lds16(vgl + (size_t)(i * 256 + tid) * 8,
                  (ushort*)Vls[0] + (i * 256 + tid) * 8);

    // K for QK(0) (transient) and QK(1) (persistent Ka)
    bf16x8 Kc0 = *(const bf16x8*)(kgl);
    bf16x8 Kc1 = *(const bf16x8*)(kgl + 2048);
    bf16x8 Ka0 = *(const bf16x8*)(kgl + 2 * 2048);
    bf16x8 Ka1 = *(const bf16x8*)(kgl + 3 * 2048);
    bf16x8 Kn0, Kn1;

    // QK(0): S^T slices D[m=4q+reg][r=16rt+l15], persist into the loop
    f32x4 S0[4], S1[4];
    __builtin_amdgcn_s_setprio(1);
#pragma unroll
    for (int rt = 0; rt < 4; ++rt)
        S0[rt] = __builtin_amdgcn_mfma_f32_16x16x32_bf16(
            Kc0, Qf[rt], (f32x4){0.f, 0.f, 0.f, 0.f}, 0, 0, 0);
#pragma unroll
    for (int rt = 0; rt < 4; ++rt)
        S1[rt] = __builtin_amdgcn_mfma_f32_16x16x32_bf16(
            Kc1, Qf[rt], (f32x4){0.f, 0.f, 0.f, 0.f}, 0, 0, 0);
    __builtin_amdgcn_s_setprio(0);

    for (int pt = 0; pt < 32; ++pt) {
        __syncthreads();   // buf[pt&1] DMA landed; buf[pt^1] readers done

        // Va prefetch: all 8 PV A-fragments issued NOW; they land under the
        // DMA/K issue + exp + QK(pt+1) phases (~1500cy >> 120cy latency).
        const ushort* vb = Vls[pt & 1] + 32 * w + 8 * q;
        bf16x8 Va[8];
#pragma unroll
        for (int cvt = 0; cvt < 8; ++cvt)
            Va[cvt] = *(const bf16x8*)(vb + (16 * cvt + l15) * 144);

        if (pt < 31) {     // async prefetch pair pt+1 into the other buffer
            const ushort* src = vgl + (size_t)(pt + 1) * 36864;
            ushort* dst = (ushort*)Vls[(pt + 1) & 1];
#pragma unroll
            for (int i = 0; i < 9; ++i)
                gld_lds16(src + (size_t)(i * 256 + tid) * 8, dst + (i * 256 + tid) * 8);
        }
        if (pt < 30) {     // K for QK(pt+2), consumed 1.5 iters from now
            Kn0 = *(const bf16x8*)(kgl + (size_t)(2 * pt + 4) * 2048);
            Kn1 = *(const bf16x8*)(kgl + (size_t)(2 * pt + 5) * 2048);
        }

        // exp(pt): S -> Pb (trans+VALU), independent of QK(pt+1) below
        bf16x8 Pb[4];
#pragma unroll
        for (int rt = 0; rt < 4; ++rt) {
            float e0 = fexp2(S0[rt][0]), e1 = fexp2(S0[rt][1]);
            float e2 = fexp2(S0[rt][2]), e3 = fexp2(S0[rt][3]);
            float f0 = fexp2(S1[rt][0]), f1 = fexp2(S1[rt][1]);
            float f2 = fexp2(S1[rt][2]), f3 = fexp2(S1[rt][3]);
            l_acc[rt] += ((e0 + e1) + (e2 + e3)) + ((f0 + f1) + (f2 + f3));
            bf16x8 p;
            p[0] = (short)bfbits(e0); p[1] = (short)bfbits(e1);
            p[2] = (short)bfbits(e2); p[3] = (short)bfbits(e3);
            p[4] = (short)bfbits(f0); p[5] = (short)bfbits(f1);
            p[6] = (short)bfbits(f2); p[7] = (short)bfbits(f3);
            Pb[rt] = p;
        }

        // QK(pt+1): overwrites S (read above); MFMA pipe fills exp stalls
        if (pt < 31) {
            __builtin_amdgcn_s_setprio(1);
#pragma unroll
            for (int rt = 0; rt < 4; ++rt)
                S0[rt] = __builtin_amdgcn_mfma_f32_16x16x32_bf16(
                    Ka0, Qf[rt], (f32x4){0.f, 0.f, 0.f, 0.f}, 0, 0, 0);
#pragma unroll
            for (int rt = 0; rt < 4; ++rt)
                S1[rt] = __builtin_amdgcn_mfma_f32_16x16x32_bf16(
                    Ka1, Qf[rt], (f32x4){0.f, 0.f, 0.f, 0.f}, 0, 0, 0);
            __builtin_amdgcn_s_setprio(0);
            Ka0 = Kn0; Ka1 = Kn1;
        }

        // PV(pt): pure register MFMA burst (Va prefetched at iter top)
        __builtin_amdgcn_s_setprio(1);
#pragma unroll
        for (int cvt = 0; cvt < 8; ++cvt) {
#pragma unroll
            for (int rt = 0; rt < 4; ++rt)
                acc[cvt][rt] = __builtin_amdgcn_mfma_f32_16x16x32_bf16(
                    Va[cvt], Pb[rt], acc[cvt][rt], 0, 0, 0);
        }
        __builtin_amdgcn_s_setprio(0);
    }

    // l: reduce over quads (shfl) then across 4 waves (lbuf)
#pragma unroll
    for (int rt = 0; rt < 4; ++rt) {
        float v = l_acc[rt];
        v += __shfl_xor(v, 16);
        v += __shfl_xor(v, 32);
        if (lane < 16) lbuf[(w * 4 + rt) * 16 + lane] = v;
    }
    __syncthreads();
    // this thread's epilogue rows are r = 16w + l15 (rt = w)
    const float linv = 1.f / (lbuf[(0 + w) * 16 + l15] + lbuf[(4 + w) * 16 + l15] +
                              lbuf[(8 + w) * 16 + l15] + lbuf[(12 + w) * 16 + l15]);
    const float gl = gptr[0] * linv;

    // cross-wave O reduction in 8 cvt chunks; Obuf aliases Vls[0]
    f32x4* Obuf = (f32x4*)&Vls[0][0];
#pragma unroll
    for (int cvt = 0; cvt < 8; ++cvt) {
        __syncthreads();
#pragma unroll
        for (int rt = 0; rt < 4; ++rt)
            Obuf[(w * 64 + lane) * 5 + rt] = acc[cvt][rt];
        __syncthreads();
        f32x4 o = Obuf[lane * 5 + w];
        o += Obuf[(64 + lane) * 5 + w];
        o += Obuf[(128 + lane) * 5 + w];
        o += Obuf[(192 + lane) * 5 + w];
        // cv = 128cvh + 16cvt + 4q + reg -> c = 32cvh + 4cvt + q, d = reg
        size_t addr = ((size_t)(b * CH + 32 * cvh + 4 * cvt + q) * NN
                       + (r0 + 16 * w + l15)) * 4;
        float4 xr = *(const float4*)(x3d + addr);
        float4 res;
        res.x = fmaf(gl, o[0], xr.x);
        res.y = fmaf(gl, o[1], xr.y);
        res.z = fmaf(gl, o[2], xr.z);
        res.w = fmaf(gl, o[3], xr.w);
        *(float4*)(out + addr) = res;
    }
}

extern "C" void kernel_launch(void* const* d_in, const int* in_sizes, int n_in,
                              void* d_out, int out_size, void* d_ws, size_t ws_size,
                              hipStream_t stream)
{
    const float* x2d = (const float*)d_in[0];
    const float* x3d = (const float*)d_in[1];
    const float* Wq  = (const float*)d_in[2];
    const float* bq  = (const float*)d_in[3];
    const float* Wk  = (const float*)d_in[4];
    const float* bk  = (const float*)d_in[5];
    const float* Wv  = (const float*)d_in[6];
    const float* bv  = (const float*)d_in[7];
    const float* gma = (const float*)d_in[8];

    ushort* wsb = (ushort*)d_ws;

    qkv_kernel<<<512, 256, 0, stream>>>(x2d, Wq, bq, Wk, bk, Wv, bv,
                                        wsb + QB_OFF, wsb + KB_OFF, wsb + VT_OFF);
    flash_kernel<<<512, 256, 0, stream>>>(wsb + QB_OFF, wsb + KB_OFF, wsb + VT_OFF,
                                          x3d, gma, (float*)d_out);
}

// Round 13
// 156.404 us; speedup vs baseline: 1.0768x; 1.0768x over previous
//
#include <hip/hip_runtime.h>
#include <hip/hip_bf16.h>

// B=4, C=64, H=W=64, D=4, CQ=8. N=H*W=4096, f_qk=32, f_v=256. I/O fp32.
// R23 = R19 two-kernel (57.4us flash best; R22's cooperative fusion REVERTED
// — coop launch silently no-ops inside graph capture, absmax 468) + bf16
// conversion via v_cvt_pk_bf16_f32 inline asm (no builtin on gfx950, T12).
// Why: R19 VALUBusy 35% > MfmaUtil 31% — VALU is the largest pipe. 32
// __float2bfloat16 per pt = 4-5 VALU each (RNE bias + NaN-check) ~= 150
// VALU/pt, the biggest VALU block. cvt_pk does 2 conversions in 1 instr,
// RNE, bit-identical on finite inputs -> 16 instrs/pt. Same in qkv (40
// conversions/thread). No layout/sync/memory changes.
// Carried: R19 rotation (exp(pt) || QK(pt+1) -> PV(pt)), R12 V staging +
// per-pt barrier, XCD affinity (FETCH 31.8->14.9MB verified), log2e-in-Q +
// asm v_exp_f32, setprio. Reg budget note: flash is exactly full at
// 128 arch + 128 acc; do not add live VGPRs (R21: +64 -> spill, +8.7MB WRITE).
#define CH 64
#define NN 4096
#define SS 16384

typedef __attribute__((ext_vector_type(8))) short bf16x8;
typedef __attribute__((ext_vector_type(4))) float f32x4;

// ws layout (ushort elems): Qb (B,N,32) | Kb (B,N,32) |
// Vt [b][sup:32][cv:256][slot:144] (128 data slots + 16 pad)
#define QB_OFF 0
#define KB_OFF 524288
#define VT_OFF 1048576

// 2^x in one HW instruction (trans pipe).
static __device__ __forceinline__ float fexp2(float x) {
    float r;
    asm("v_exp_f32 %0, %1" : "=v"(r) : "v"(x));
    return r;
}

// 2 f32 -> packed bf16x2 in one instr (RNE; lo = cvt(a), hi = cvt(b)).
static __device__ __forceinline__ uint cvtpk(float a, float b) {
    uint r;
    asm("v_cvt_pk_bf16_f32 %0, %1, %2" : "=v"(r) : "v"(a), "v"(b));
    return r;
}

static __device__ __forceinline__ void gld_lds16(const ushort* g, ushort* l) {
    __builtin_amdgcn_global_load_lds(
        (const __attribute__((address_space(1))) void*)g,
        (__attribute__((address_space(3))) void*)l, 16, 0, 0);
}

// ---------------- qkv ----------------
// grid 512. XCD-affine decode: xcd = blk&7 owns batch xcd>>1; the 4 og
// blocks of one (b,sup) share an XCD so the 128KB x-slab is fetched into
// one L2 once. 256 threads = (nl = tid>>2, d).
// og0: q8 + v[0:12); og1: k8 + v[12:24); og2: v[24:44); og3: v[44:64).
__global__ __launch_bounds__(256) void qkv_kernel(
    const float* __restrict__ x,
    const float* __restrict__ Wq, const float* __restrict__ bq,
    const float* __restrict__ Wk, const float* __restrict__ bk,
    const float* __restrict__ Wv, const float* __restrict__ bv,
    ushort* __restrict__ qb, ushort* __restrict__ kb, ushort* __restrict__ vt)
{
    __shared__ __align__(16) ushort Tqk[128 * 40];  // [n_loc][f], q or k
    __shared__ __align__(16) ushort Tv[80 * 144];   // [cv_loc][slot]

    const int blk = blockIdx.x;
    const int xcd = blk & 7, jb = blk >> 3;          // jb in [0,64)
    const int b = xcd >> 1;
    const int sup = ((xcd & 1) << 4) | (jb & 15);
    const int og = jb >> 4;
    const int tid = threadIdx.x;
    const int nl = tid >> 2, d = tid & 3;

    const int vcnt = (og < 2) ? 12 : 20;
    const int vo0 = (og == 0) ? 0 : (og == 1) ? 12 : (og == 2) ? 24 : 44;

    // fold log2(e) into q so flash computes exp(s) as 2^s (v_exp_f32 direct)
    const float qscale = (og == 0) ? 1.4426950408889634f : 1.0f;

    const float* xb = x + (size_t)b * CH * SS + sup * 512;

    for (int t = 0; t < 2; ++t) {
        const float* xp = xb + t * 256 + tid;
        float xr[CH];
#pragma unroll
        for (int c = 0; c < CH; ++c) xr[c] = xp[(size_t)c * SS];

        // flash pair-interleave: m_loc = nl of tile t -> slot
        const int slot = 32 * (nl >> 4) + 8 * ((nl >> 2) & 3) + 4 * t + (nl & 3);

        if (og < 2) {
            const float* Wqk = (og == 0) ? Wq : Wk;
            const float* bqk = (og == 0) ? bq : bk;
            ushort* trow = &Tqk[(t * 64 + nl) * 40 + d];
#pragma unroll
            for (int o = 0; o < 8; o += 2) {
                float a0 = bqk[o], a1 = bqk[o + 1];
#pragma unroll
                for (int c = 0; c < CH; ++c) {
                    a0 = fmaf(Wqk[o * CH + c],       xr[c], a0);
                    a1 = fmaf(Wqk[(o + 1) * CH + c], xr[c], a1);
                }
                uint wp = cvtpk(a0 * qscale, a1 * qscale);
                trow[o * 4]       = (ushort)wp;
                trow[(o + 1) * 4] = (ushort)(wp >> 16);
            }
        }
        ushort* vcol = &Tv[d * 144 + slot];
        const float* Wvb = Wv + vo0 * CH;
        const float* bvb = bv + vo0;
        if (og < 2) {
#pragma unroll
            for (int j = 0; j < 12; j += 2) {
                float a0 = bvb[j], a1 = bvb[j + 1];
#pragma unroll
                for (int c = 0; c < CH; ++c) {
                    a0 = fmaf(Wvb[j * CH + c],       xr[c], a0);
                    a1 = fmaf(Wvb[(j + 1) * CH + c], xr[c], a1);
                }
                uint wp = cvtpk(a0, a1);
                vcol[(j * 4) * 144]       = (ushort)wp;
                vcol[((j + 1) * 4) * 144] = (ushort)(wp >> 16);
            }
        } else {
#pragma unroll
            for (int j = 0; j < 20; j += 2) {
                float a0 = bvb[j], a1 = bvb[j + 1];
#pragma unroll
                for (int c = 0; c < CH; ++c) {
                    a0 = fmaf(Wvb[j * CH + c],       xr[c], a0);
                    a1 = fmaf(Wvb[(j + 1) * CH + c], xr[c], a1);
                }
                uint wp = cvtpk(a0, a1);
                vcol[(j * 4) * 144]       = (ushort)wp;
                vcol[((j + 1) * 4) * 144] = (ushort)(wp >> 16);
            }
        }
    }
    __syncthreads();

    // Q/K readout: 128 rows x 32 ushorts = 512 uint4 chunks, 2 per thread
    if (og < 2) {
        ushort* dst = (og == 0 ? qb : kb);
#pragma unroll
        for (int jj = 0; jj < 2; ++jj) {
            int idx = jj * 256 + tid;
            int row = idx >> 2, seg = idx & 3;
            *(uint4*)(dst + ((size_t)(b * NN + sup * 128 + row)) * 32 + seg * 8)
                = *(const uint4*)&Tqk[row * 40 + seg * 8];
        }
    }
    // V readout: vcnt*4 rows x 128 data slots = vcnt*64 uint4 chunks
    const int nchunks = vcnt * 64;   // 768 (og<2) or 1280 (og>=2)
    ushort* vout = vt + ((size_t)((b * 32 + sup) * 256 + vo0 * 4)) * 144;
#pragma unroll
    for (int j = 0; j < 5; ++j) {
        int idx = j * 256 + tid;
        if (idx < nchunks) {
            int row = idx >> 4, seg = idx & 15;
            *(uint4*)(vout + (size_t)row * 144 + seg * 8)
                = *(const uint4*)&Tv[row * 144 + seg * 8];
        }
    }
}

// ---------------- flash ----------------
// grid 512. XCD-affine decode: xcd = blk&7 -> batch xcd>>1, cv-half xcd&1,
// r-tile = blk>>3. 256 threads = 4 waves; wave w owns m-slice [16w,16w+16)
// of each 64-m tile; pair pt = 2 tiles = 32 k. V staged async global->LDS,
// double-buffered, one barrier per pt. Pipeline rotation: iter pt does
// exp(pt), QK(pt+1), PV(pt); S and Ka persist across iters.
__global__ __launch_bounds__(256, 2) void flash_kernel(
    const ushort* __restrict__ qb, const ushort* __restrict__ kb,
    const ushort* __restrict__ vt, const float* __restrict__ x3d,
    const float* __restrict__ gptr, float* __restrict__ out)
{
    __shared__ __align__(16) ushort Vls[2][128 * 144];  // [cv'][slot], dbuf
    __shared__ float lbuf[4 * 4 * 16];

    const int tid = threadIdx.x;
    const int xcd = blockIdx.x & 7, jb = blockIdx.x >> 3;  // jb in [0,64)
    const int b   = xcd >> 1;
    const int r0  = (jb & 63) << 6;
    const int cvh = xcd & 1;
    const int w = tid >> 6, lane = tid & 63, q = lane >> 4, l15 = lane & 15;

    // Q B-frags (16x16x32): B[f=8q+j][r=16rt+l15]
    bf16x8 Qf[4];
#pragma unroll
    for (int rt = 0; rt < 4; ++rt)
        Qf[rt] = *(const bf16x8*)(qb + (size_t)(b * NN + r0 + 16 * rt + l15) * 32 + 8 * q);

    f32x4 acc[8][4];
#pragma unroll
    for (int i = 0; i < 8; ++i)
#pragma unroll
        for (int j = 0; j < 4; ++j) acc[i][j] = (f32x4){0.f, 0.f, 0.f, 0.f};
    float l_acc[4] = {0.f, 0.f, 0.f, 0.f};

    // K rows for wave w, tile mt: kb[(mt*64 + 16w + l15)*32 + 8q]
    const ushort* kgl = kb + (size_t)b * NN * 32 + (16 * w + l15) * 32 + 8 * q;

    // V stream: block's 128-cv half of each sup = 128*144 ushorts contiguous
    const ushort* vgl = vt + ((size_t)(b * 32) * 256 + 128 * cvh) * 144;

    // async stage pair 0 -> buf 0 (wave-uniform base + lane*16: valid DMA)
#pragma unroll
    for (int i = 0; i < 9; ++i)
        gld_lds16(vgl + (size_t)(i * 256 + tid) * 8,
                  (ushort*)Vls[0] + (i * 256 + tid) * 8);

    // K for QK(0) (transient) and QK(1) (persistent Ka)
    bf16x8 Kc0 = *(const bf16x8*)(kgl);
    bf16x8 Kc1 = *(const bf16x8*)(kgl + 2048);
    bf16x8 Ka0 = *(const bf16x8*)(kgl + 2 * 2048);
    bf16x8 Ka1 = *(const bf16x8*)(kgl + 3 * 2048);
    bf16x8 Kn0, Kn1;

    // QK(0): S^T slices D[m=4q+reg][r=16rt+l15], persist into the loop
    f32x4 S0[4], S1[4];
    __builtin_amdgcn_s_setprio(1);
#pragma unroll
    for (int rt = 0; rt < 4; ++rt)
        S0[rt] = __builtin_amdgcn_mfma_f32_16x16x32_bf16(
            Kc0, Qf[rt], (f32x4){0.f, 0.f, 0.f, 0.f}, 0, 0, 0);
#pragma unroll
    for (int rt = 0; rt < 4; ++rt)
        S1[rt] = __builtin_amdgcn_mfma_f32_16x16x32_bf16(
            Kc1, Qf[rt], (f32x4){0.f, 0.f, 0.f, 0.f}, 0, 0, 0);
    __builtin_amdgcn_s_setprio(0);

    for (int pt = 0; pt < 32; ++pt) {
        __syncthreads();   // buf[pt&1] DMA landed; buf[pt^1] readers done
        if (pt < 31) {     // async prefetch pair pt+1 into the other buffer
            const ushort* src = vgl + (size_t)(pt + 1) * 36864;
            ushort* dst = (ushort*)Vls[(pt + 1) & 1];
#pragma unroll
            for (int i = 0; i < 9; ++i)
                gld_lds16(src + (size_t)(i * 256 + tid) * 8, dst + (i * 256 + tid) * 8);
        }
        if (pt < 30) {     // K for QK(pt+2), consumed 1.5 iters from now
            Kn0 = *(const bf16x8*)(kgl + (size_t)(2 * pt + 4) * 2048);
            Kn1 = *(const bf16x8*)(kgl + (size_t)(2 * pt + 5) * 2048);
        }

        // exp(pt): S -> Pb. 32 exp (trans) + 16 v_cvt_pk_bf16_f32 (VALU,
        // was ~150 VALU with scalar __float2bfloat16) + 28 adds for l.
        bf16x8 Pb[4];
#pragma unroll
        for (int rt = 0; rt < 4; ++rt) {
            float e0 = fexp2(S0[rt][0]), e1 = fexp2(S0[rt][1]);
            float e2 = fexp2(S0[rt][2]), e3 = fexp2(S0[rt][3]);
            float f0 = fexp2(S1[rt][0]), f1 = fexp2(S1[rt][1]);
            float f2 = fexp2(S1[rt][2]), f3 = fexp2(S1[rt][3]);
            l_acc[rt] += ((e0 + e1) + (e2 + e3)) + ((f0 + f1) + (f2 + f3));
            union { uint u[4]; bf16x8 v; } pk;
            pk.u[0] = cvtpk(e0, e1);
            pk.u[1] = cvtpk(e2, e3);
            pk.u[2] = cvtpk(f0, f1);
            pk.u[3] = cvtpk(f2, f3);
            Pb[rt] = pk.v;
        }

        // QK(pt+1): overwrites S (read above); MFMA pipe fills exp stalls
        if (pt < 31) {
            __builtin_amdgcn_s_setprio(1);
#pragma unroll
            for (int rt = 0; rt < 4; ++rt)
                S0[rt] = __builtin_amdgcn_mfma_f32_16x16x32_bf16(
                    Ka0, Qf[rt], (f32x4){0.f, 0.f, 0.f, 0.f}, 0, 0, 0);
#pragma unroll
            for (int rt = 0; rt < 4; ++rt)
                S1[rt] = __builtin_amdgcn_mfma_f32_16x16x32_bf16(
                    Ka1, Qf[rt], (f32x4){0.f, 0.f, 0.f, 0.f}, 0, 0, 0);
            __builtin_amdgcn_s_setprio(0);
            Ka0 = Kn0; Ka1 = Kn1;
        }

        // PV(pt): A[cv=16cvt+l15][k=8q+j] = one ds_read_b128
        const ushort* vb = Vls[pt & 1] + 32 * w + 8 * q;
        __builtin_amdgcn_s_setprio(1);
#pragma unroll
        for (int cvt = 0; cvt < 8; ++cvt) {
            bf16x8 Va = *(const bf16x8*)(vb + (16 * cvt + l15) * 144);
#pragma unroll
            for (int rt = 0; rt < 4; ++rt)
                acc[cvt][rt] = __builtin_amdgcn_mfma_f32_16x16x32_bf16(
                    Va, Pb[rt], acc[cvt][rt], 0, 0, 0);
        }
        __builtin_amdgcn_s_setprio(0);
    }

    // l: reduce over quads (shfl) then across 4 waves (lbuf)
#pragma unroll
    for (int rt = 0; rt < 4; ++rt) {
        float v = l_acc[rt];
        v += __shfl_xor(v, 16);
        v += __shfl_xor(v, 32);
        if (lane < 16) lbuf[(w * 4 + rt) * 16 + lane] = v;
    }
    __syncthreads();
    // this thread's epilogue rows are r = 16w + l15 (rt = w)
    const float linv = 1.f / (lbuf[(0 + w) * 16 + l15] + lbuf[(4 + w) * 16 + l15] +
                              lbuf[(8 + w) * 16 + l15] + lbuf[(12 + w) * 16 + l15]);
    const float gl = gptr[0] * linv;

    // cross-wave O reduction in 8 cvt chunks; Obuf aliases Vls[0]
    f32x4* Obuf = (f32x4*)&Vls[0][0];
#pragma unroll
    for (int cvt = 0; cvt < 8; ++cvt) {
        __syncthreads();
#pragma unroll
        for (int rt = 0; rt < 4; ++rt)
            Obuf[(w * 64 + lane) * 5 + rt] = acc[cvt][rt];
        __syncthreads();
        f32x4 o = Obuf[lane * 5 + w];
        o += Obuf[(64 + lane) * 5 + w];
        o += Obuf[(128 + lane) * 5 + w];
        o += Obuf[(192 + lane) * 5 + w];
        // cv = 128cvh + 16cvt + 4q + reg -> c = 32cvh + 4cvt + q, d = reg
        size_t addr = ((size_t)(b * CH + 32 * cvh + 4 * cvt + q) * NN
                       + (r0 + 16 * w + l15)) * 4;
        float4 xr = *(const float4*)(x3d + addr);
        float4 res;
        res.x = fmaf(gl, o[0], xr.x);
        res.y = fmaf(gl, o[1], xr.y);
        res.z = fmaf(gl, o[2], xr.z);
        res.w = fmaf(gl, o[3], xr.w);
        *(float4*)(out + addr) = res;
    }
}

extern "C" void kernel_launch(void* const* d_in, const int* in_sizes, int n_in,
                              void* d_out, int out_size, void* d_ws, size_t ws_size,
                              hipStream_t stream)
{
    const float* x2d = (const float*)d_in[0];
    const float* x3d = (const float*)d_in[1];
    const float* Wq  = (const float*)d_in[2];
    const float* bq  = (const float*)d_in[3];
    const float* Wk  = (const float*)d_in[4];
    const float* bk  = (const float*)d_in[5];
    const float* Wv  = (const float*)d_in[6];
    const float* bv  = (const float*)d_in[7];
    const float* gma = (const float*)d_in[8];

    ushort* wsb = (ushort*)d_ws;

    qkv_kernel<<<512, 256, 0, stream>>>(x2d, Wq, bq, Wk, bk, Wv, bv,
                                        wsb + QB_OFF, wsb + KB_OFF, wsb + VT_OFF);
    flash_kernel<<<512, 256, 0, stream>>>(wsb + QB_OFF, wsb + KB_OFF, wsb + VT_OFF,
                                          x3d, gma, (float*)d_out);
}

// Round 14
// 143.058 us; speedup vs baseline: 1.1773x; 1.0933x over previous
//
#include <hip/hip_runtime.h>
#include <hip/hip_bf16.h>

// B=4, C=64, H=W=64, D=4, CQ=8. N=H*W=4096, f_qk=32, f_v=256. I/O fp32.
// R24 = R23 flash (54.5us, byte-identical) + qkv REWRITTEN AS MFMA GEMM.
// Evidence: qkv+overhead = 106.9+-1.2us across R12-R21; R23's cvt_pk (-6%
// qkv instrs) moved total by -5.5us beyond flash's delta -> qkv ~= 45-55us
// on the VALU (80x64 x 64x16384 matmul = 671 GFLOP, serial 64-deep FMA
// chains). MFMA form: block = (b,sup,schunk128): stage W->LDS bf16 [80][72]
// (log2e folded into Wq/bq), x-slab->LDS bf16 [128][72] (float4 coalesced,
// cvt_pk, b128 writes), 20 mfma 16x16x32/wave with flash's verified lane
// maps (A[m=l15][k=8q+j], B[k=8q+j][r=l15], D[m=4q+reg][r=l15]); outputs
// scatter-stored to the BYTE-IDENTICAL Qb/Kb/Vt layouts (slot map
// re-derived; flash untouched). x read once (16MB, was 4x via og blocks).
// Numerics: x,W rounded to bf16 pre-matmul -> absmax ~2x (est 0.03-0.05,
// threshold 0.104).
// Carried: XCD affinity both kernels, R19 rotation + R23 cvt_pk in flash.
#define CH 64
#define NN 4096
#define SS 16384
#define LOG2E 1.4426950408889634f

typedef __attribute__((ext_vector_type(8))) short bf16x8;
typedef __attribute__((ext_vector_type(4))) float f32x4;

// ws layout (ushort elems): Qb (B,N,32) | Kb (B,N,32) |
// Vt [b][sup:32][cv:256][slot:144] (128 data slots + 16 pad)
#define QB_OFF 0
#define KB_OFF 524288
#define VT_OFF 1048576

// 2^x in one HW instruction (trans pipe).
static __device__ __forceinline__ float fexp2(float x) {
    float r;
    asm("v_exp_f32 %0, %1" : "=v"(r) : "v"(x));
    return r;
}

// 2 f32 -> packed bf16x2 in one instr (RNE; lo = cvt(a), hi = cvt(b)).
static __device__ __forceinline__ uint cvtpk(float a, float b) {
    uint r;
    asm("v_cvt_pk_bf16_f32 %0, %1, %2" : "=v"(r) : "v"(a), "v"(b));
    return r;
}

static __device__ __forceinline__ void gld_lds16(const ushort* g, ushort* l) {
    __builtin_amdgcn_global_load_lds(
        (const __attribute__((address_space(1))) void*)g,
        (__attribute__((address_space(3))) void*)l, 16, 0, 0);
}

// ---------------- qkv (MFMA) ----------------
// grid 512 = xcd(8) x jb(64): b = xcd>>1, sup = ((xcd&1)<<4)|(jb&15),
// schunk = jb>>4. Block computes out[80][128] = W[80][64] x x[64][128]
// for s in [sup*512 + schunk*128, +128). W rows: 0-7 q (xLOG2E), 8-15 k,
// 16-79 v. 256 threads = 4 waves; wave w owns ntiles {2w, 2w+1}.
__global__ __launch_bounds__(256) void qkv_kernel(
    const float* __restrict__ x,
    const float* __restrict__ Wq, const float* __restrict__ bq,
    const float* __restrict__ Wk, const float* __restrict__ bk,
    const float* __restrict__ Wv, const float* __restrict__ bv,
    ushort* __restrict__ qb, ushort* __restrict__ kb, ushort* __restrict__ vt)
{
    __shared__ __align__(16) ushort Wl[80 * 72];   // [m][c], pad 72
    __shared__ __align__(16) ushort Xl[128 * 72];  // [s_loc][c], pad 72
    __shared__ __align__(16) float  Bl[80];

    const int blk = blockIdx.x;
    const int xcd = blk & 7, jb = blk >> 3;
    const int b = xcd >> 1;
    const int sup = ((xcd & 1) << 4) | (jb & 15);
    const int sch = jb >> 4;
    const int tid = threadIdx.x;

    // ---- stage W (bf16) ----
#pragma unroll
    for (int r = 0; r < 2; ++r) {   // q rows 0-7, log2e folded
        int idx = r * 256 + tid, m = idx >> 6, c = idx & 63;
        Wl[m * 72 + c] = (ushort)(cvtpk(Wq[m * 64 + c] * LOG2E, 0.f) & 0xffff);
    }
#pragma unroll
    for (int r = 0; r < 2; ++r) {   // k rows 8-15
        int idx = r * 256 + tid, m = idx >> 6, c = idx & 63;
        Wl[(8 + m) * 72 + c] = (ushort)(cvtpk(Wk[m * 64 + c], 0.f) & 0xffff);
    }
#pragma unroll
    for (int r = 0; r < 16; ++r) {  // v rows 16-79
        int idx = r * 256 + tid, m = idx >> 6, c = idx & 63;
        Wl[(16 + m) * 72 + c] = (ushort)(cvtpk(Wv[m * 64 + c], 0.f) & 0xffff);
    }
    if (tid < 80)
        Bl[tid] = (tid < 8) ? bq[tid] * LOG2E
                : (tid < 16) ? bk[tid - 8] : bv[tid - 16];

    // ---- stage x (bf16, transposed to [s][c]) ----
    // thread: s-quad slot32 = tid&31 (4 s each), channels cb*8..cb*8+7.
    const int slot32 = tid & 31, cb = tid >> 5;
    const int s0 = sup * 512 + sch * 128;
    const float* xb = x + (size_t)(b * 64 + cb * 8) * SS + s0 + 4 * slot32;
    uint ru[4][4];  // ru[v][j]: bf16 pair (c = cb*8+2j, 2j+1) at s = 4*slot32+v
#pragma unroll
    for (int j = 0; j < 4; ++j) {
        float4 fA = *(const float4*)(xb + (2 * j) * SS);
        float4 fB = *(const float4*)(xb + (2 * j + 1) * SS);
        ru[0][j] = cvtpk(fA.x, fB.x);
        ru[1][j] = cvtpk(fA.y, fB.y);
        ru[2][j] = cvtpk(fA.z, fB.z);
        ru[3][j] = cvtpk(fA.w, fB.w);
    }
#pragma unroll
    for (int v = 0; v < 4; ++v) {
        uint4 pk = make_uint4(ru[0][0], ru[0][1], ru[0][2], ru[0][3]);
        // note: must write row_v's 8 c-values: ru[v][0..3]
        pk = make_uint4(ru[v][0], ru[v][1], ru[v][2], ru[v][3]);
        *(uint4*)&Xl[(4 * slot32 + v) * 72 + cb * 8] = pk;
    }
    __syncthreads();

    // ---- MFMA + store ----
    const int w = tid >> 6, lane = tid & 63, q = lane >> 4, l15 = lane & 15;
#pragma unroll
    for (int i = 0; i < 2; ++i) {
        const int nt = 2 * w + i;
        bf16x8 b0 = *(const bf16x8*)&Xl[(nt * 16 + l15) * 72 + 8 * q];
        bf16x8 b1 = *(const bf16x8*)&Xl[(nt * 16 + l15) * 72 + 8 * q + 32];

        // lane spatial indices (D column r = l15)
        const int s_loc = nt * 16 + l15;
        const int dd = l15 & 3;
        const int nsup = sch * 32 + nt * 4 + (l15 >> 2);
        const int t = nsup >> 6, nl = nsup & 63;
        const int slot = 32 * (nl >> 4) + 8 * ((nl >> 2) & 3) + 4 * t + (nl & 3);
        const int n = sup * 128 + nsup;
        (void)s_loc;

#pragma unroll
        for (int mt = 0; mt < 5; ++mt) {
            bf16x8 a0 = *(const bf16x8*)&Wl[(mt * 16 + l15) * 72 + 8 * q];
            bf16x8 a1 = *(const bf16x8*)&Wl[(mt * 16 + l15) * 72 + 8 * q + 32];
            f32x4 acc = __builtin_amdgcn_mfma_f32_16x16x32_bf16(
                a0, b0, (f32x4){0.f, 0.f, 0.f, 0.f}, 0, 0, 0);
            acc = __builtin_amdgcn_mfma_f32_16x16x32_bf16(a1, b1, acc, 0, 0, 0);
            f32x4 bias = *(const f32x4*)&Bl[mt * 16 + 4 * q];
            acc += bias;
            uint u01 = cvtpk(acc[0], acc[1]);
            uint u23 = cvtpk(acc[2], acc[3]);
            if (mt == 0) {
                // m = 4q+reg: q<2 -> Q (f = 16q+4reg+dd), else K
                ushort* dst = (q < 2)
                    ? qb + ((size_t)(b * NN + n)) * 32 + 16 * q + dd
                    : kb + ((size_t)(b * NN + n)) * 32 + 16 * (q - 2) + dd;
                dst[0]  = (ushort)u01;
                dst[4]  = (ushort)(u01 >> 16);
                dst[8]  = (ushort)u23;
                dst[12] = (ushort)(u23 >> 16);
            } else {
                // ch_v = (mt-1)*16 + 4q + reg; cv = ch_v*4 + dd
                ushort* dst = vt + ((size_t)((b * 32 + sup) * 256
                              + ((mt - 1) * 16 + 4 * q) * 4 + dd)) * 144 + slot;
                dst[0 * 576] = (ushort)u01;           // reg 0 (cv stride 4*144)
                dst[1 * 576] = (ushort)(u01 >> 16);   // reg 1
                dst[2 * 576] = (ushort)u23;           // reg 2
                dst[3 * 576] = (ushort)(u23 >> 16);   // reg 3
            }
        }
    }
}

// ---------------- flash ---------------- (R23, unchanged)
// grid 512. XCD-affine decode: xcd = blk&7 -> batch xcd>>1, cv-half xcd&1,
// r-tile = blk>>3. 256 threads = 4 waves; wave w owns m-slice [16w,16w+16)
// of each 64-m tile; pair pt = 2 tiles = 32 k. V staged async global->LDS,
// double-buffered, one barrier per pt. Pipeline rotation: iter pt does
// exp(pt), QK(pt+1), PV(pt); S and Ka persist across iters.
__global__ __launch_bounds__(256, 2) void flash_kernel(
    const ushort* __restrict__ qb, const ushort* __restrict__ kb,
    const ushort* __restrict__ vt, const float* __restrict__ x3d,
    const float* __restrict__ gptr, float* __restrict__ out)
{
    __shared__ __align__(16) ushort Vls[2][128 * 144];  // [cv'][slot], dbuf
    __shared__ float lbuf[4 * 4 * 16];

    const int tid = threadIdx.x;
    const int xcd = blockIdx.x & 7, jb = blockIdx.x >> 3;  // jb in [0,64)
    const int b   = xcd >> 1;
    const int r0  = (jb & 63) << 6;
    const int cvh = xcd & 1;
    const int w = tid >> 6, lane = tid & 63, q = lane >> 4, l15 = lane & 15;

    // Q B-frags (16x16x32): B[f=8q+j][r=16rt+l15]
    bf16x8 Qf[4];
#pragma unroll
    for (int rt = 0; rt < 4; ++rt)
        Qf[rt] = *(const bf16x8*)(qb + (size_t)(b * NN + r0 + 16 * rt + l15) * 32 + 8 * q);

    f32x4 acc[8][4];
#pragma unroll
    for (int i = 0; i < 8; ++i)
#pragma unroll
        for (int j = 0; j < 4; ++j) acc[i][j] = (f32x4){0.f, 0.f, 0.f, 0.f};
    float l_acc[4] = {0.f, 0.f, 0.f, 0.f};

    // K rows for wave w, tile mt: kb[(mt*64 + 16w + l15)*32 + 8q]
    const ushort* kgl = kb + (size_t)b * NN * 32 + (16 * w + l15) * 32 + 8 * q;

    // V stream: block's 128-cv half of each sup = 128*144 ushorts contiguous
    const ushort* vgl = vt + ((size_t)(b * 32) * 256 + 128 * cvh) * 144;

    // async stage pair 0 -> buf 0 (wave-uniform base + lane*16: valid DMA)
#pragma unroll
    for (int i = 0; i < 9; ++i)
        gld_lds16(vgl + (size_t)(i * 256 + tid) * 8,
                  (ushort*)Vls[0] + (i * 256 + tid) * 8);

    // K for QK(0) (transient) and QK(1) (persistent Ka)
    bf16x8 Kc0 = *(const bf16x8*)(kgl);
    bf16x8 Kc1 = *(const bf16x8*)(kgl + 2048);
    bf16x8 Ka0 = *(const bf16x8*)(kgl + 2 * 2048);
    bf16x8 Ka1 = *(const bf16x8*)(kgl + 3 * 2048);
    bf16x8 Kn0, Kn1;

    // QK(0): S^T slices D[m=4q+reg][r=16rt+l15], persist into the loop
    f32x4 S0[4], S1[4];
    __builtin_amdgcn_s_setprio(1);
#pragma unroll
    for (int rt = 0; rt < 4; ++rt)
        S0[rt] = __builtin_amdgcn_mfma_f32_16x16x32_bf16(
            Kc0, Qf[rt], (f32x4){0.f, 0.f, 0.f, 0.f}, 0, 0, 0);
#pragma unroll
    for (int rt = 0; rt < 4; ++rt)
        S1[rt] = __builtin_amdgcn_mfma_f32_16x16x32_bf16(
            Kc1, Qf[rt], (f32x4){0.f, 0.f, 0.f, 0.f}, 0, 0, 0);
    __builtin_amdgcn_s_setprio(0);

    for (int pt = 0; pt < 32; ++pt) {
        __syncthreads();   // buf[pt&1] DMA landed; buf[pt^1] readers done
        if (pt < 31) {     // async prefetch pair pt+1 into the other buffer
            const ushort* src = vgl + (size_t)(pt + 1) * 36864;
            ushort* dst = (ushort*)Vls[(pt + 1) & 1];
#pragma unroll
            for (int i = 0; i < 9; ++i)
                gld_lds16(src + (size_t)(i * 256 + tid) * 8, dst + (i * 256 + tid) * 8);
        }
        if (pt < 30) {     // K for QK(pt+2), consumed 1.5 iters from now
            Kn0 = *(const bf16x8*)(kgl + (size_t)(2 * pt + 4) * 2048);
            Kn1 = *(const bf16x8*)(kgl + (size_t)(2 * pt + 5) * 2048);
        }

        // exp(pt): S -> Pb. 32 exp (trans) + 16 v_cvt_pk_bf16_f32 (VALU).
        bf16x8 Pb[4];
#pragma unroll
        for (int rt = 0; rt < 4; ++rt) {
            float e0 = fexp2(S0[rt][0]), e1 = fexp2(S0[rt][1]);
            float e2 = fexp2(S0[rt][2]), e3 = fexp2(S0[rt][3]);
            float f0 = fexp2(S1[rt][0]), f1 = fexp2(S1[rt][1]);
            float f2 = fexp2(S1[rt][2]), f3 = fexp2(S1[rt][3]);
            l_acc[rt] += ((e0 + e1) + (e2 + e3)) + ((f0 + f1) + (f2 + f3));
            union { uint u[4]; bf16x8 v; } pk;
            pk.u[0] = cvtpk(e0, e1);
            pk.u[1] = cvtpk(e2, e3);
            pk.u[2] = cvtpk(f0, f1);
            pk.u[3] = cvtpk(f2, f3);
            Pb[rt] = pk.v;
        }

        // QK(pt+1): overwrites S (read above); MFMA pipe fills exp stalls
        if (pt < 31) {
            __builtin_amdgcn_s_setprio(1);
#pragma unroll
            for (int rt = 0; rt < 4; ++rt)
                S0[rt] = __builtin_amdgcn_mfma_f32_16x16x32_bf16(
                    Ka0, Qf[rt], (f32x4){0.f, 0.f, 0.f, 0.f}, 0, 0, 0);
#pragma unroll
            for (int rt = 0; rt < 4; ++rt)
                S1[rt] = __builtin_amdgcn_mfma_f32_16x16x32_bf16(
                    Ka1, Qf[rt], (f32x4){0.f, 0.f, 0.f, 0.f}, 0, 0, 0);
            __builtin_amdgcn_s_setprio(0);
            Ka0 = Kn0; Ka1 = Kn1;
        }

        // PV(pt): A[cv=16cvt+l15][k=8q+j] = one ds_read_b128
        const ushort* vb = Vls[pt & 1] + 32 * w + 8 * q;
        __builtin_amdgcn_s_setprio(1);
#pragma unroll
        for (int cvt = 0; cvt < 8; ++cvt) {
            bf16x8 Va = *(const bf16x8*)(vb + (16 * cvt + l15) * 144);
#pragma unroll
            for (int rt = 0; rt < 4; ++rt)
                acc[cvt][rt] = __builtin_amdgcn_mfma_f32_16x16x32_bf16(
                    Va, Pb[rt], acc[cvt][rt], 0, 0, 0);
        }
        __builtin_amdgcn_s_setprio(0);
    }

    // l: reduce over quads (shfl) then across 4 waves (lbuf)
#pragma unroll
    for (int rt = 0; rt < 4; ++rt) {
        float v = l_acc[rt];
        v += __shfl_xor(v, 16);
        v += __shfl_xor(v, 32);
        if (lane < 16) lbuf[(w * 4 + rt) * 16 + lane] = v;
    }
    __syncthreads();
    // this thread's epilogue rows are r = 16w + l15 (rt = w)
    const float linv = 1.f / (lbuf[(0 + w) * 16 + l15] + lbuf[(4 + w) * 16 + l15] +
                              lbuf[(8 + w) * 16 + l15] + lbuf[(12 + w) * 16 + l15]);
    const float gl = gptr[0] * linv;

    // cross-wave O reduction in 8 cvt chunks; Obuf aliases Vls[0]
    f32x4* Obuf = (f32x4*)&Vls[0][0];
#pragma unroll
    for (int cvt = 0; cvt < 8; ++cvt) {
        __syncthreads();
#pragma unroll
        for (int rt = 0; rt < 4; ++rt)
            Obuf[(w * 64 + lane) * 5 + rt] = acc[cvt][rt];
        __syncthreads();
        f32x4 o = Obuf[lane * 5 + w];
        o += Obuf[(64 + lane) * 5 + w];
        o += Obuf[(128 + lane) * 5 + w];
        o += Obuf[(192 + lane) * 5 + w];
        // cv = 128cvh + 16cvt + 4q + reg -> c = 32cvh + 4cvt + q, d = reg
        size_t addr = ((size_t)(b * CH + 32 * cvh + 4 * cvt + q) * NN
                       + (r0 + 16 * w + l15)) * 4;
        float4 xr = *(const float4*)(x3d + addr);
        float4 res;
        res.x = fmaf(gl, o[0], xr.x);
        res.y = fmaf(gl, o[1], xr.y);
        res.z = fmaf(gl, o[2], xr.z);
        res.w = fmaf(gl, o[3], xr.w);
        *(float4*)(out + addr) = res;
    }
}

extern "C" void kernel_launch(void* const* d_in, const int* in_sizes, int n_in,
                              void* d_out, int out_size, void* d_ws, size_t ws_size,
                              hipStream_t stream)
{
    const float* x2d = (const float*)d_in[0];
    const float* x3d = (const float*)d_in[1];
    const float* Wq  = (const float*)d_in[2];
    const float* bq  = (const float*)d_in[3];
    const float* Wk  = (const float*)d_in[4];
    const float* bk  = (const float*)d_in[5];
    const float* Wv  = (const float*)d_in[6];
    const float* bv  = (const float*)d_in[7];
    const float* gma = (const float*)d_in[8];

    ushort* wsb = (ushort*)d_ws;

    qkv_kernel<<<512, 256, 0, stream>>>(x2d, Wq, bq, Wk, bk, Wv, bv,
                                        wsb + QB_OFF, wsb + KB_OFF, wsb + VT_OFF);
    flash_kernel<<<512, 256, 0, stream>>>(wsb + QB_OFF, wsb + KB_OFF, wsb + VT_OFF,
                                          x3d, gma, (float*)d_out);
}

// Round 15
// 140.584 us; speedup vs baseline: 1.1980x; 1.0176x over previous
//
#include <hip/hip_runtime.h>
#include <hip/hip_bf16.h>

// B=4, C=64, H=W=64, D=4, CQ=8. N=H*W=4096, f_qk=32, f_v=256. I/O fp32.
// R25 = R24 (143.1us) with the MFMA-qkv epilogue restored to LDS-transpose
// + coalesced stores. R24's qkv scattered 40x 2-byte global stores per
// thread (Q/K stride 4 ush, V stride 576) -> L2 read-for-ownership on every
// line + 40 serialized VMEM instrs; the old VALU qkv used LDS staging + 7
// uint4 stores. Now: MFMA D-frags -> QKt[32n][Q32|K32] and Vtl[256cv][32]
// LDS tiles (disjoint from live Wl/Xl), one barrier, then readout: Q/K as
// 256 uint4, V as 2048 uint2 (slot map has 4-contiguous runs: slot =
// 32*(nlq>>2)+8*(nlq&3)+4*t+e, nlq=(sch*8+run)&15, t=sch>>1 — re-derived
// and matched against the flash-verified Vt layout for all sch). Same
// bytes, full-line coalesced. LDS 53.3KB. Flash byte-identical to R23/R24
// (54.5-58.5 band; if it returns to ~54.5 the R24 drift was qkv's dirty
// partial lines in L2).
// Carried: qkv as MFMA GEMM (x read once, W->LDS bf16, log2e in Wq/bq),
// XCD affinity both kernels, R19 rotation + cvt_pk in flash.
#define CH 64
#define NN 4096
#define SS 16384
#define LOG2E 1.4426950408889634f

typedef __attribute__((ext_vector_type(8))) short bf16x8;
typedef __attribute__((ext_vector_type(4))) float f32x4;

// ws layout (ushort elems): Qb (B,N,32) | Kb (B,N,32) |
// Vt [b][sup:32][cv:256][slot:144] (128 data slots + 16 pad)
#define QB_OFF 0
#define KB_OFF 524288
#define VT_OFF 1048576

// 2^x in one HW instruction (trans pipe).
static __device__ __forceinline__ float fexp2(float x) {
    float r;
    asm("v_exp_f32 %0, %1" : "=v"(r) : "v"(x));
    return r;
}

// 2 f32 -> packed bf16x2 in one instr (RNE; lo = cvt(a), hi = cvt(b)).
static __device__ __forceinline__ uint cvtpk(float a, float b) {
    uint r;
    asm("v_cvt_pk_bf16_f32 %0, %1, %2" : "=v"(r) : "v"(a), "v"(b));
    return r;
}

static __device__ __forceinline__ void gld_lds16(const ushort* g, ushort* l) {
    __builtin_amdgcn_global_load_lds(
        (const __attribute__((address_space(1))) void*)g,
        (__attribute__((address_space(3))) void*)l, 16, 0, 0);
}

// ---------------- qkv (MFMA) ----------------
// grid 512 = xcd(8) x jb(64): b = xcd>>1, sup = ((xcd&1)<<4)|(jb&15),
// schunk = jb>>4. Block computes out[80][128] = W[80][64] x x[64][128]
// for s in [sup*512 + sch*128, +128). W rows: 0-7 q (xLOG2E), 8-15 k,
// 16-79 v. 256 threads = 4 waves; wave w owns ntiles {2w, 2w+1}.
__global__ __launch_bounds__(256) void qkv_kernel(
    const float* __restrict__ x,
    const float* __restrict__ Wq, const float* __restrict__ bq,
    const float* __restrict__ Wk, const float* __restrict__ bk,
    const float* __restrict__ Wv, const float* __restrict__ bv,
    ushort* __restrict__ qb, ushort* __restrict__ kb, ushort* __restrict__ vt)
{
    __shared__ __align__(16) ushort Wl[80 * 72];    // [m][c], pad 72
    __shared__ __align__(16) ushort Xl[128 * 72];   // [s_loc][c], pad 72
    __shared__ __align__(16) ushort QKt[32 * 72];   // [nloc][Q 0-31 | K 32-63]
    __shared__ __align__(16) ushort Vtl[256 * 36];  // [cv][nloc compact]
    __shared__ __align__(16) float  Bl[80];

    const int blk = blockIdx.x;
    const int xcd = blk & 7, jb = blk >> 3;
    const int b = xcd >> 1;
    const int sup = ((xcd & 1) << 4) | (jb & 15);
    const int sch = jb >> 4;
    const int tid = threadIdx.x;

    // ---- stage W (bf16) ----
#pragma unroll
    for (int r = 0; r < 2; ++r) {   // q rows 0-7, log2e folded
        int idx = r * 256 + tid, m = idx >> 6, c = idx & 63;
        Wl[m * 72 + c] = (ushort)(cvtpk(Wq[m * 64 + c] * LOG2E, 0.f) & 0xffff);
    }
#pragma unroll
    for (int r = 0; r < 2; ++r) {   // k rows 8-15
        int idx = r * 256 + tid, m = idx >> 6, c = idx & 63;
        Wl[(8 + m) * 72 + c] = (ushort)(cvtpk(Wk[m * 64 + c], 0.f) & 0xffff);
    }
#pragma unroll
    for (int r = 0; r < 16; ++r) {  // v rows 16-79
        int idx = r * 256 + tid, m = idx >> 6, c = idx & 63;
        Wl[(16 + m) * 72 + c] = (ushort)(cvtpk(Wv[m * 64 + c], 0.f) & 0xffff);
    }
    if (tid < 80)
        Bl[tid] = (tid < 8) ? bq[tid] * LOG2E
                : (tid < 16) ? bk[tid - 8] : bv[tid - 16];

    // ---- stage x (bf16, transposed to [s][c]) ----
    // thread: s-quad slot32 = tid&31 (4 s each), channels cb*8..cb*8+7.
    const int slot32 = tid & 31, cb = tid >> 5;
    const int s0 = sup * 512 + sch * 128;
    const float* xb = x + (size_t)(b * 64 + cb * 8) * SS + s0 + 4 * slot32;
    uint ru[4][4];  // ru[v][j]: bf16 pair (c = cb*8+2j, 2j+1) at s = 4*slot32+v
#pragma unroll
    for (int j = 0; j < 4; ++j) {
        float4 fA = *(const float4*)(xb + (2 * j) * SS);
        float4 fB = *(const float4*)(xb + (2 * j + 1) * SS);
        ru[0][j] = cvtpk(fA.x, fB.x);
        ru[1][j] = cvtpk(fA.y, fB.y);
        ru[2][j] = cvtpk(fA.z, fB.z);
        ru[3][j] = cvtpk(fA.w, fB.w);
    }
#pragma unroll
    for (int v = 0; v < 4; ++v) {
        uint4 pk = make_uint4(ru[v][0], ru[v][1], ru[v][2], ru[v][3]);
        *(uint4*)&Xl[(4 * slot32 + v) * 72 + cb * 8] = pk;
    }
    __syncthreads();

    // ---- MFMA -> LDS staging tiles ----
    const int w = tid >> 6, lane = tid & 63, q = lane >> 4, l15 = lane & 15;
    const int dd = l15 & 3;
#pragma unroll
    for (int i = 0; i < 2; ++i) {
        const int nt = 2 * w + i;
        bf16x8 b0 = *(const bf16x8*)&Xl[(nt * 16 + l15) * 72 + 8 * q];
        bf16x8 b1 = *(const bf16x8*)&Xl[(nt * 16 + l15) * 72 + 8 * q + 32];

        const int nloc = nt * 4 + (l15 >> 2);   // n within block's 32-row span

#pragma unroll
        for (int mt = 0; mt < 5; ++mt) {
            bf16x8 a0 = *(const bf16x8*)&Wl[(mt * 16 + l15) * 72 + 8 * q];
            bf16x8 a1 = *(const bf16x8*)&Wl[(mt * 16 + l15) * 72 + 8 * q + 32];
            f32x4 acc = __builtin_amdgcn_mfma_f32_16x16x32_bf16(
                a0, b0, (f32x4){0.f, 0.f, 0.f, 0.f}, 0, 0, 0);
            acc = __builtin_amdgcn_mfma_f32_16x16x32_bf16(a1, b1, acc, 0, 0, 0);
            f32x4 bias = *(const f32x4*)&Bl[mt * 16 + 4 * q];
            acc += bias;
            uint u01 = cvtpk(acc[0], acc[1]);
            uint u23 = cvtpk(acc[2], acc[3]);
            if (mt == 0) {
                // m = 4q+reg -> Q col m*4+dd (q<2) or K col 32+(m-8)*4+dd
                const int base = (q < 2) ? (16 * q + dd) : (32 + 16 * (q - 2) + dd);
                ushort* dst = &QKt[nloc * 72 + base];
                dst[0]  = (ushort)u01;
                dst[4]  = (ushort)(u01 >> 16);
                dst[8]  = (ushort)u23;
                dst[12] = (ushort)(u23 >> 16);
            } else {
                // ch_v = (mt-1)*16+4q+reg; cv = ch_v*4+dd (stride 4 per reg)
                const int cv0 = ((mt - 1) * 16 + 4 * q) * 4 + dd;
                Vtl[(cv0 +  0) * 36 + nloc] = (ushort)u01;
                Vtl[(cv0 +  4) * 36 + nloc] = (ushort)(u01 >> 16);
                Vtl[(cv0 +  8) * 36 + nloc] = (ushort)u23;
                Vtl[(cv0 + 12) * 36 + nloc] = (ushort)(u23 >> 16);
            }
        }
    }
    __syncthreads();

    // ---- coalesced readout ----
    // Q/K: 32 rows x (32+32) ushorts = 256 uint4, 1 per thread
    {
        const int row = tid >> 3, seg = tid & 7;
        const int n = sup * 128 + sch * 32 + row;
        if (seg < 4)
            *(uint4*)(qb + ((size_t)(b * NN + n)) * 32 + seg * 8)
                = *(const uint4*)&QKt[row * 72 + seg * 8];
        else
            *(uint4*)(kb + ((size_t)(b * NN + n)) * 32 + (seg - 4) * 8)
                = *(const uint4*)&QKt[row * 72 + 32 + (seg - 4) * 8];
    }
    // V: 256 cv x 8 runs of 4 slots = 2048 uint2, 8 per thread.
    // global slot for nloc = run*4+e: nlq = (sch*8+run)&15, t = sch>>1,
    // slot = 32*(nlq>>2) + 8*(nlq&3) + 4*t + e  (4-contiguous, 8B-aligned)
    {
        ushort* vbase = vt + ((size_t)((b * 32 + sup) * 256)) * 144;
        const int t4 = (sch >> 1) * 4;
#pragma unroll
        for (int j = 0; j < 8; ++j) {
            int idx = j * 256 + tid;
            int cv = idx >> 3, run = idx & 7;
            int nlq = (sch * 8 + run) & 15;
            int slot0 = 32 * (nlq >> 2) + 8 * (nlq & 3) + t4;
            *(uint2*)(vbase + (size_t)cv * 144 + slot0)
                = *(const uint2*)&Vtl[cv * 36 + run * 4];
        }
    }
}

// ---------------- flash ---------------- (R23/R24, unchanged)
// grid 512. XCD-affine decode: xcd = blk&7 -> batch xcd>>1, cv-half xcd&1,
// r-tile = blk>>3. 256 threads = 4 waves; wave w owns m-slice [16w,16w+16)
// of each 64-m tile; pair pt = 2 tiles = 32 k. V staged async global->LDS,
// double-buffered, one barrier per pt. Pipeline rotation: iter pt does
// exp(pt), QK(pt+1), PV(pt); S and Ka persist across iters.
__global__ __launch_bounds__(256, 2) void flash_kernel(
    const ushort* __restrict__ qb, const ushort* __restrict__ kb,
    const ushort* __restrict__ vt, const float* __restrict__ x3d,
    const float* __restrict__ gptr, float* __restrict__ out)
{
    __shared__ __align__(16) ushort Vls[2][128 * 144];  // [cv'][slot], dbuf
    __shared__ float lbuf[4 * 4 * 16];

    const int tid = threadIdx.x;
    const int xcd = blockIdx.x & 7, jb = blockIdx.x >> 3;  // jb in [0,64)
    const int b   = xcd >> 1;
    const int r0  = (jb & 63) << 6;
    const int cvh = xcd & 1;
    const int w = tid >> 6, lane = tid & 63, q = lane >> 4, l15 = lane & 15;

    // Q B-frags (16x16x32): B[f=8q+j][r=16rt+l15]
    bf16x8 Qf[4];
#pragma unroll
    for (int rt = 0; rt < 4; ++rt)
        Qf[rt] = *(const bf16x8*)(qb + (size_t)(b * NN + r0 + 16 * rt + l15) * 32 + 8 * q);

    f32x4 acc[8][4];
#pragma unroll
    for (int i = 0; i < 8; ++i)
#pragma unroll
        for (int j = 0; j < 4; ++j) acc[i][j] = (f32x4){0.f, 0.f, 0.f, 0.f};
    float l_acc[4] = {0.f, 0.f, 0.f, 0.f};

    // K rows for wave w, tile mt: kb[(mt*64 + 16w + l15)*32 + 8q]
    const ushort* kgl = kb + (size_t)b * NN * 32 + (16 * w + l15) * 32 + 8 * q;

    // V stream: block's 128-cv half of each sup = 128*144 ushorts contiguous
    const ushort* vgl = vt + ((size_t)(b * 32) * 256 + 128 * cvh) * 144;

    // async stage pair 0 -> buf 0 (wave-uniform base + lane*16: valid DMA)
#pragma unroll
    for (int i = 0; i < 9; ++i)
        gld_lds16(vgl + (size_t)(i * 256 + tid) * 8,
                  (ushort*)Vls[0] + (i * 256 + tid) * 8);

    // K for QK(0) (transient) and QK(1) (persistent Ka)
    bf16x8 Kc0 = *(const bf16x8*)(kgl);
    bf16x8 Kc1 = *(const bf16x8*)(kgl + 2048);
    bf16x8 Ka0 = *(const bf16x8*)(kgl + 2 * 2048);
    bf16x8 Ka1 = *(const bf16x8*)(kgl + 3 * 2048);
    bf16x8 Kn0, Kn1;

    // QK(0): S^T slices D[m=4q+reg][r=16rt+l15], persist into the loop
    f32x4 S0[4], S1[4];
    __builtin_amdgcn_s_setprio(1);
#pragma unroll
    for (int rt = 0; rt < 4; ++rt)
        S0[rt] = __builtin_amdgcn_mfma_f32_16x16x32_bf16(
            Kc0, Qf[rt], (f32x4){0.f, 0.f, 0.f, 0.f}, 0, 0, 0);
#pragma unroll
    for (int rt = 0; rt < 4; ++rt)
        S1[rt] = __builtin_amdgcn_mfma_f32_16x16x32_bf16(
            Kc1, Qf[rt], (f32x4){0.f, 0.f, 0.f, 0.f}, 0, 0, 0);
    __builtin_amdgcn_s_setprio(0);

    for (int pt = 0; pt < 32; ++pt) {
        __syncthreads();   // buf[pt&1] DMA landed; buf[pt^1] readers done
        if (pt < 31) {     // async prefetch pair pt+1 into the other buffer
            const ushort* src = vgl + (size_t)(pt + 1) * 36864;
            ushort* dst = (ushort*)Vls[(pt + 1) & 1];
#pragma unroll
            for (int i = 0; i < 9; ++i)
                gld_lds16(src + (size_t)(i * 256 + tid) * 8, dst + (i * 256 + tid) * 8);
        }
        if (pt < 30) {     // K for QK(pt+2), consumed 1.5 iters from now
            Kn0 = *(const bf16x8*)(kgl + (size_t)(2 * pt + 4) * 2048);
            Kn1 = *(const bf16x8*)(kgl + (size_t)(2 * pt + 5) * 2048);
        }

        // exp(pt): S -> Pb. 32 exp (trans) + 16 v_cvt_pk_bf16_f32 (VALU).
        bf16x8 Pb[4];
#pragma unroll
        for (int rt = 0; rt < 4; ++rt) {
            float e0 = fexp2(S0[rt][0]), e1 = fexp2(S0[rt][1]);
            float e2 = fexp2(S0[rt][2]), e3 = fexp2(S0[rt][3]);
            float f0 = fexp2(S1[rt][0]), f1 = fexp2(S1[rt][1]);
            float f2 = fexp2(S1[rt][2]), f3 = fexp2(S1[rt][3]);
            l_acc[rt] += ((e0 + e1) + (e2 + e3)) + ((f0 + f1) + (f2 + f3));
            union { uint u[4]; bf16x8 v; } pk;
            pk.u[0] = cvtpk(e0, e1);
            pk.u[1] = cvtpk(e2, e3);
            pk.u[2] = cvtpk(f0, f1);
            pk.u[3] = cvtpk(f2, f3);
            Pb[rt] = pk.v;
        }

        // QK(pt+1): overwrites S (read above); MFMA pipe fills exp stalls
        if (pt < 31) {
            __builtin_amdgcn_s_setprio(1);
#pragma unroll
            for (int rt = 0; rt < 4; ++rt)
                S0[rt] = __builtin_amdgcn_mfma_f32_16x16x32_bf16(
                    Ka0, Qf[rt], (f32x4){0.f, 0.f, 0.f, 0.f}, 0, 0, 0);
#pragma unroll
            for (int rt = 0; rt < 4; ++rt)
                S1[rt] = __builtin_amdgcn_mfma_f32_16x16x32_bf16(
                    Ka1, Qf[rt], (f32x4){0.f, 0.f, 0.f, 0.f}, 0, 0, 0);
            __builtin_amdgcn_s_setprio(0);
            Ka0 = Kn0; Ka1 = Kn1;
        }

        // PV(pt): A[cv=16cvt+l15][k=8q+j] = one ds_read_b128
        const ushort* vb = Vls[pt & 1] + 32 * w + 8 * q;
        __builtin_amdgcn_s_setprio(1);
#pragma unroll
        for (int cvt = 0; cvt < 8; ++cvt) {
            bf16x8 Va = *(const bf16x8*)(vb + (16 * cvt + l15) * 144);
#pragma unroll
            for (int rt = 0; rt < 4; ++rt)
                acc[cvt][rt] = __builtin_amdgcn_mfma_f32_16x16x32_bf16(
                    Va, Pb[rt], acc[cvt][rt], 0, 0, 0);
        }
        __builtin_amdgcn_s_setprio(0);
    }

    // l: reduce over quads (shfl) then across 4 waves (lbuf)
#pragma unroll
    for (int rt = 0; rt < 4; ++rt) {
        float v = l_acc[rt];
        v += __shfl_xor(v, 16);
        v += __shfl_xor(v, 32);
        if (lane < 16) lbuf[(w * 4 + rt) * 16 + lane] = v;
    }
    __syncthreads();
    // this thread's epilogue rows are r = 16w + l15 (rt = w)
    const float linv = 1.f / (lbuf[(0 + w) * 16 + l15] + lbuf[(4 + w) * 16 + l15] +
                              lbuf[(8 + w) * 16 + l15] + lbuf[(12 + w) * 16 + l15]);
    const float gl = gptr[0] * linv;

    // cross-wave O reduction in 8 cvt chunks; Obuf aliases Vls[0]
    f32x4* Obuf = (f32x4*)&Vls[0][0];
#pragma unroll
    for (int cvt = 0; cvt < 8; ++cvt) {
        __syncthreads();
#pragma unroll
        for (int rt = 0; rt < 4; ++rt)
            Obuf[(w * 64 + lane) * 5 + rt] = acc[cvt][rt];
        __syncthreads();
        f32x4 o = Obuf[lane * 5 + w];
        o += Obuf[(64 + lane) * 5 + w];
        o += Obuf[(128 + lane) * 5 + w];
        o += Obuf[(192 + lane) * 5 + w];
        // cv = 128cvh + 16cvt + 4q + reg -> c = 32cvh + 4cvt + q, d = reg
        size_t addr = ((size_t)(b * CH + 32 * cvh + 4 * cvt + q) * NN
                       + (r0 + 16 * w + l15)) * 4;
        float4 xr = *(const float4*)(x3d + addr);
        float4 res;
        res.x = fmaf(gl, o[0], xr.x);
        res.y = fmaf(gl, o[1], xr.y);
        res.z = fmaf(gl, o[2], xr.z);
        res.w = fmaf(gl, o[3], xr.w);
        *(float4*)(out + addr) = res;
    }
}

extern "C" void kernel_launch(void* const* d_in, const int* in_sizes, int n_in,
                              void* d_out, int out_size, void* d_ws, size_t ws_size,
                              hipStream_t stream)
{
    const float* x2d = (const float*)d_in[0];
    const float* x3d = (const float*)d_in[1];
    const float* Wq  = (const float*)d_in[2];
    const float* bq  = (const float*)d_in[3];
    const float* Wk  = (const float*)d_in[4];
    const float* bk  = (const float*)d_in[5];
    const float* Wv  = (const float*)d_in[6];
    const float* bv  = (const float*)d_in[7];
    const float* gma = (const float*)d_in[8];

    ushort* wsb = (ushort*)d_ws;

    qkv_kernel<<<512, 256, 0, stream>>>(x2d, Wq, bq, Wk, bk, Wv, bv,
                                        wsb + QB_OFF, wsb + KB_OFF, wsb + VT_OFF);
    flash_kernel<<<512, 256, 0, stream>>>(wsb + QB_OFF, wsb + KB_OFF, wsb + VT_OFF,
                                          x3d, gma, (float*)d_out);
}

// Round 16
// 138.211 us; speedup vs baseline: 1.2186x; 1.0172x over previous
//
#include <hip/hip_runtime.h>
#include <hip/hip_bf16.h>

// B=4, C=64, H=W=64, D=4, CQ=8. N=H*W=4096, f_qk=32, f_v=256. I/O fp32.
// R26 = R25 (140.6us) with qkv parallelism DOUBLED: s-chunk 128 -> 64,
// grid 512 -> 1024 (= 4 blocks/CU resident, LDS 53.3 -> 33.3KB). R25
// accounting: flash locked at 53.7 (structural floor: MfmaUtil 32% =
// 17.2us pure MFMA / 53.7), non-flash = 86.9 = qkv + fixed harness
// overhead (dozens of memset/restore dispatches in the timed graph).
// qkv at 512 blocks = 2/CU had flash's old disease: long serial prologue
// (20 W-stage rounds -> barrier -> MFMA -> barrier -> readout), 8 waves/CU.
// Halving per-block work + 2x blocks/CU hides the latency. Slot map for
// 64-s blocks: slot = 32*(sch6&3) + 8*run + 4*(sch6>>2) + e (re-derived,
// no carry: (sch6&3)*16+15 <= 63; matches flash-verified Vt layout).
// Identical FP order -> bit-identical output (absmax 0.03125).
// Flash BYTE-IDENTICAL to R25 -> Δtotal = Δqkv (discriminates qkv~35
// [total -> ~128] vs qkv~12 [total -> ~136] models).
// Carried: qkv MFMA GEMM + LDS-transpose epilogue, XCD affinity, R19
// rotation + cvt_pk + setprio in flash, log2e folded into Wq/bq.
#define CH 64
#define NN 4096
#define SS 16384
#define LOG2E 1.4426950408889634f

typedef __attribute__((ext_vector_type(8))) short bf16x8;
typedef __attribute__((ext_vector_type(4))) float f32x4;

// ws layout (ushort elems): Qb (B,N,32) | Kb (B,N,32) |
// Vt [b][sup:32][cv:256][slot:144] (128 data slots + 16 pad)
#define QB_OFF 0
#define KB_OFF 524288
#define VT_OFF 1048576

// 2^x in one HW instruction (trans pipe).
static __device__ __forceinline__ float fexp2(float x) {
    float r;
    asm("v_exp_f32 %0, %1" : "=v"(r) : "v"(x));
    return r;
}

// 2 f32 -> packed bf16x2 in one instr (RNE; lo = cvt(a), hi = cvt(b)).
static __device__ __forceinline__ uint cvtpk(float a, float b) {
    uint r;
    asm("v_cvt_pk_bf16_f32 %0, %1, %2" : "=v"(r) : "v"(a), "v"(b));
    return r;
}

static __device__ __forceinline__ void gld_lds16(const ushort* g, ushort* l) {
    __builtin_amdgcn_global_load_lds(
        (const __attribute__((address_space(1))) void*)g,
        (__attribute__((address_space(3))) void*)l, 16, 0, 0);
}

// ---------------- qkv (MFMA, 64-s blocks) ----------------
// grid 1024 = xcd(8) x jb(128): b = xcd>>1, sup = ((xcd&1)<<4)|(jb&15),
// sch6 = jb>>4 in [0,8). Block computes out[80][64] = W[80][64] x x[64][64]
// for s in [sup*512 + sch6*64, +64) = 16 n x 4 d. W rows: 0-7 q (xLOG2E),
// 8-15 k, 16-79 v. 256 threads = 4 waves; wave w owns ntile w.
__global__ __launch_bounds__(256) void qkv_kernel(
    const float* __restrict__ x,
    const float* __restrict__ Wq, const float* __restrict__ bq,
    const float* __restrict__ Wk, const float* __restrict__ bk,
    const float* __restrict__ Wv, const float* __restrict__ bv,
    ushort* __restrict__ qb, ushort* __restrict__ kb, ushort* __restrict__ vt)
{
    __shared__ __align__(16) ushort Wl[80 * 72];    // [m][c], pad 72
    __shared__ __align__(16) ushort Xl[64 * 72];    // [s_loc][c], pad 72
    __shared__ __align__(16) ushort QKt[16 * 72];   // [nloc][Q 0-31 | K 32-63]
    __shared__ __align__(16) ushort Vtl[256 * 20];  // [cv][nloc compact, pad 20]
    __shared__ __align__(16) float  Bl[80];

    const int blk = blockIdx.x;
    const int xcd = blk & 7, jb = blk >> 3;          // jb in [0,128)
    const int b = xcd >> 1;
    const int sup = ((xcd & 1) << 4) | (jb & 15);
    const int sch = jb >> 4;                         // [0,8)
    const int tid = threadIdx.x;

    // ---- stage W (bf16) ----
#pragma unroll
    for (int r = 0; r < 2; ++r) {   // q rows 0-7, log2e folded
        int idx = r * 256 + tid, m = idx >> 6, c = idx & 63;
        Wl[m * 72 + c] = (ushort)(cvtpk(Wq[m * 64 + c] * LOG2E, 0.f) & 0xffff);
    }
#pragma unroll
    for (int r = 0; r < 2; ++r) {   // k rows 8-15
        int idx = r * 256 + tid, m = idx >> 6, c = idx & 63;
        Wl[(8 + m) * 72 + c] = (ushort)(cvtpk(Wk[m * 64 + c], 0.f) & 0xffff);
    }
#pragma unroll
    for (int r = 0; r < 16; ++r) {  // v rows 16-79
        int idx = r * 256 + tid, m = idx >> 6, c = idx & 63;
        Wl[(16 + m) * 72 + c] = (ushort)(cvtpk(Wv[m * 64 + c], 0.f) & 0xffff);
    }
    if (tid < 80)
        Bl[tid] = (tid < 8) ? bq[tid] * LOG2E
                : (tid < 16) ? bk[tid - 8] : bv[tid - 16];

    // ---- stage x (bf16, transposed to [s][c]) ----
    // thread: s-quad sq = tid&15 (4 s each -> 64 s), channels cb*4..cb*4+3.
    const int sq = tid & 15, cb = tid >> 4;
    const int s0 = sup * 512 + sch * 64;
    const float* xb = x + (size_t)(b * 64 + cb * 4) * SS + s0 + 4 * sq;
    uint ru[4][2];  // ru[v][j]: bf16 pair (c = cb*4+2j, 2j+1) at s = 4*sq+v
#pragma unroll
    for (int j = 0; j < 2; ++j) {
        float4 fA = *(const float4*)(xb + (2 * j) * SS);
        float4 fB = *(const float4*)(xb + (2 * j + 1) * SS);
        ru[0][j] = cvtpk(fA.x, fB.x);
        ru[1][j] = cvtpk(fA.y, fB.y);
        ru[2][j] = cvtpk(fA.z, fB.z);
        ru[3][j] = cvtpk(fA.w, fB.w);
    }
#pragma unroll
    for (int v = 0; v < 4; ++v) {
        uint2 pk = make_uint2(ru[v][0], ru[v][1]);
        *(uint2*)&Xl[(4 * sq + v) * 72 + cb * 4] = pk;
    }
    __syncthreads();

    // ---- MFMA -> LDS staging tiles ----
    const int w = tid >> 6, lane = tid & 63, q = lane >> 4, l15 = lane & 15;
    const int dd = l15 & 3;
    {
        bf16x8 b0 = *(const bf16x8*)&Xl[(w * 16 + l15) * 72 + 8 * q];
        bf16x8 b1 = *(const bf16x8*)&Xl[(w * 16 + l15) * 72 + 8 * q + 32];

        const int nloc = w * 4 + (l15 >> 2);   // n within block's 16-row span

#pragma unroll
        for (int mt = 0; mt < 5; ++mt) {
            bf16x8 a0 = *(const bf16x8*)&Wl[(mt * 16 + l15) * 72 + 8 * q];
            bf16x8 a1 = *(const bf16x8*)&Wl[(mt * 16 + l15) * 72 + 8 * q + 32];
            f32x4 acc = __builtin_amdgcn_mfma_f32_16x16x32_bf16(
                a0, b0, (f32x4){0.f, 0.f, 0.f, 0.f}, 0, 0, 0);
            acc = __builtin_amdgcn_mfma_f32_16x16x32_bf16(a1, b1, acc, 0, 0, 0);
            f32x4 bias = *(const f32x4*)&Bl[mt * 16 + 4 * q];
            acc += bias;
            uint u01 = cvtpk(acc[0], acc[1]);
            uint u23 = cvtpk(acc[2], acc[3]);
            if (mt == 0) {
                // m = 4q+reg -> Q col m*4+dd (q<2) or K col 32+(m-8)*4+dd
                const int base = (q < 2) ? (16 * q + dd) : (32 + 16 * (q - 2) + dd);
                ushort* dst = &QKt[nloc * 72 + base];
                dst[0]  = (ushort)u01;
                dst[4]  = (ushort)(u01 >> 16);
                dst[8]  = (ushort)u23;
                dst[12] = (ushort)(u23 >> 16);
            } else {
                // ch_v = (mt-1)*16+4q+reg; cv = ch_v*4+dd (stride 4 per reg)
                const int cv0 = ((mt - 1) * 16 + 4 * q) * 4 + dd;
                Vtl[(cv0 +  0) * 20 + nloc] = (ushort)u01;
                Vtl[(cv0 +  4) * 20 + nloc] = (ushort)(u01 >> 16);
                Vtl[(cv0 +  8) * 20 + nloc] = (ushort)u23;
                Vtl[(cv0 + 12) * 20 + nloc] = (ushort)(u23 >> 16);
            }
        }
    }
    __syncthreads();

    // ---- coalesced readout ----
    // Q/K: 16 rows x (32+32) ushorts = 128 uint4, threads 0-127
    if (tid < 128) {
        const int row = tid >> 3, seg = tid & 7;
        const int n = sup * 128 + sch * 16 + row;
        if (seg < 4)
            *(uint4*)(qb + ((size_t)(b * NN + n)) * 32 + seg * 8)
                = *(const uint4*)&QKt[row * 72 + seg * 8];
        else
            *(uint4*)(kb + ((size_t)(b * NN + n)) * 32 + (seg - 4) * 8)
                = *(const uint4*)&QKt[row * 72 + 32 + (seg - 4) * 8];
    }
    // V: 256 cv x 4 runs of 4 slots = 1024 uint2, 4 per thread.
    // nsup = sch*16 + nloc, nloc = run*4+e -> t = sch>>2, nl = (sch&3)*16+nloc
    // slot = 32*(sch&3) + 8*run + 4*(sch>>2) + e  (4-contiguous, 8B-aligned)
    {
        ushort* vbase = vt + ((size_t)((b * 32 + sup) * 256)) * 144;
        const int sbase = 32 * (sch & 3) + 4 * (sch >> 2);
#pragma unroll
        for (int j = 0; j < 4; ++j) {
            int idx = j * 256 + tid;
            int cv = idx >> 2, run = idx & 3;
            *(uint2*)(vbase + (size_t)cv * 144 + sbase + 8 * run)
                = *(const uint2*)&Vtl[cv * 20 + run * 4];
        }
    }
}

// ---------------- flash ---------------- (R25, byte-identical)
// grid 512. XCD-affine decode: xcd = blk&7 -> batch xcd>>1, cv-half xcd&1,
// r-tile = blk>>3. 256 threads = 4 waves; wave w owns m-slice [16w,16w+16)
// of each 64-m tile; pair pt = 2 tiles = 32 k. V staged async global->LDS,
// double-buffered, one barrier per pt. Pipeline rotation: iter pt does
// exp(pt), QK(pt+1), PV(pt); S and Ka persist across iters.
__global__ __launch_bounds__(256, 2) void flash_kernel(
    const ushort* __restrict__ qb, const ushort* __restrict__ kb,
    const ushort* __restrict__ vt, const float* __restrict__ x3d,
    const float* __restrict__ gptr, float* __restrict__ out)
{
    __shared__ __align__(16) ushort Vls[2][128 * 144];  // [cv'][slot], dbuf
    __shared__ float lbuf[4 * 4 * 16];

    const int tid = threadIdx.x;
    const int xcd = blockIdx.x & 7, jb = blockIdx.x >> 3;  // jb in [0,64)
    const int b   = xcd >> 1;
    const int r0  = (jb & 63) << 6;
    const int cvh = xcd & 1;
    const int w = tid >> 6, lane = tid & 63, q = lane >> 4, l15 = lane & 15;

    // Q B-frags (16x16x32): B[f=8q+j][r=16rt+l15]
    bf16x8 Qf[4];
#pragma unroll
    for (int rt = 0; rt < 4; ++rt)
        Qf[rt] = *(const bf16x8*)(qb + (size_t)(b * NN + r0 + 16 * rt + l15) * 32 + 8 * q);

    f32x4 acc[8][4];
#pragma unroll
    for (int i = 0; i < 8; ++i)
#pragma unroll
        for (int j = 0; j < 4; ++j) acc[i][j] = (f32x4){0.f, 0.f, 0.f, 0.f};
    float l_acc[4] = {0.f, 0.f, 0.f, 0.f};

    // K rows for wave w, tile mt: kb[(mt*64 + 16w + l15)*32 + 8q]
    const ushort* kgl = kb + (size_t)b * NN * 32 + (16 * w + l15) * 32 + 8 * q;

    // V stream: block's 128-cv half of each sup = 128*144 ushorts contiguous
    const ushort* vgl = vt + ((size_t)(b * 32) * 256 + 128 * cvh) * 144;

    // async stage pair 0 -> buf 0 (wave-uniform base + lane*16: valid DMA)
#pragma unroll
    for (int i = 0; i < 9; ++i)
        gld_lds16(vgl + (size_t)(i * 256 + tid) * 8,
                  (ushort*)Vls[0] + (i * 256 + tid) * 8);

    // K for QK(0) (transient) and QK(1) (persistent Ka)
    bf16x8 Kc0 = *(const bf16x8*)(kgl);
    bf16x8 Kc1 = *(const bf16x8*)(kgl + 2048);
    bf16x8 Ka0 = *(const bf16x8*)(kgl + 2 * 2048);
    bf16x8 Ka1 = *(const bf16x8*)(kgl + 3 * 2048);
    bf16x8 Kn0, Kn1;

    // QK(0): S^T slices D[m=4q+reg][r=16rt+l15], persist into the loop
    f32x4 S0[4], S1[4];
    __builtin_amdgcn_s_setprio(1);
#pragma unroll
    for (int rt = 0; rt < 4; ++rt)
        S0[rt] = __builtin_amdgcn_mfma_f32_16x16x32_bf16(
            Kc0, Qf[rt], (f32x4){0.f, 0.f, 0.f, 0.f}, 0, 0, 0);
#pragma unroll
    for (int rt = 0; rt < 4; ++rt)
        S1[rt] = __builtin_amdgcn_mfma_f32_16x16x32_bf16(
            Kc1, Qf[rt], (f32x4){0.f, 0.f, 0.f, 0.f}, 0, 0, 0);
    __builtin_amdgcn_s_setprio(0);

    for (int pt = 0; pt < 32; ++pt) {
        __syncthreads();   // buf[pt&1] DMA landed; buf[pt^1] readers done
        if (pt < 31) {     // async prefetch pair pt+1 into the other buffer
            const ushort* src = vgl + (size_t)(pt + 1) * 36864;
            ushort* dst = (ushort*)Vls[(pt + 1) & 1];
#pragma unroll
            for (int i = 0; i < 9; ++i)
                gld_lds16(src + (size_t)(i * 256 + tid) * 8, dst + (i * 256 + tid) * 8);
        }
        if (pt < 30) {     // K for QK(pt+2), consumed 1.5 iters from now
            Kn0 = *(const bf16x8*)(kgl + (size_t)(2 * pt + 4) * 2048);
            Kn1 = *(const bf16x8*)(kgl + (size_t)(2 * pt + 5) * 2048);
        }

        // exp(pt): S -> Pb. 32 exp (trans) + 16 v_cvt_pk_bf16_f32 (VALU).
        bf16x8 Pb[4];
#pragma unroll
        for (int rt = 0; rt < 4; ++rt) {
            float e0 = fexp2(S0[rt][0]), e1 = fexp2(S0[rt][1]);
            float e2 = fexp2(S0[rt][2]), e3 = fexp2(S0[rt][3]);
            float f0 = fexp2(S1[rt][0]), f1 = fexp2(S1[rt][1]);
            float f2 = fexp2(S1[rt][2]), f3 = fexp2(S1[rt][3]);
            l_acc[rt] += ((e0 + e1) + (e2 + e3)) + ((f0 + f1) + (f2 + f3));
            union { uint u[4]; bf16x8 v; } pk;
            pk.u[0] = cvtpk(e0, e1);
            pk.u[1] = cvtpk(e2, e3);
            pk.u[2] = cvtpk(f0, f1);
            pk.u[3] = cvtpk(f2, f3);
            Pb[rt] = pk.v;
        }

        // QK(pt+1): overwrites S (read above); MFMA pipe fills exp stalls
        if (pt < 31) {
            __builtin_amdgcn_s_setprio(1);
#pragma unroll
            for (int rt = 0; rt < 4; ++rt)
                S0[rt] = __builtin_amdgcn_mfma_f32_16x16x32_bf16(
                    Ka0, Qf[rt], (f32x4){0.f, 0.f, 0.f, 0.f}, 0, 0, 0);
#pragma unroll
            for (int rt = 0; rt < 4; ++rt)
                S1[rt] = __builtin_amdgcn_mfma_f32_16x16x32_bf16(
                    Ka1, Qf[rt], (f32x4){0.f, 0.f, 0.f, 0.f}, 0, 0, 0);
            __builtin_amdgcn_s_setprio(0);
            Ka0 = Kn0; Ka1 = Kn1;
        }

        // PV(pt): A[cv=16cvt+l15][k=8q+j] = one ds_read_b128
        const ushort* vb = Vls[pt & 1] + 32 * w + 8 * q;
        __builtin_amdgcn_s_setprio(1);
#pragma unroll
        for (int cvt = 0; cvt < 8; ++cvt) {
            bf16x8 Va = *(const bf16x8*)(vb + (16 * cvt + l15) * 144);
#pragma unroll
            for (int rt = 0; rt < 4; ++rt)
                acc[cvt][rt] = __builtin_amdgcn_mfma_f32_16x16x32_bf16(
                    Va, Pb[rt], acc[cvt][rt], 0, 0, 0);
        }
        __builtin_amdgcn_s_setprio(0);
    }

    // l: reduce over quads (shfl) then across 4 waves (lbuf)
#pragma unroll
    for (int rt = 0; rt < 4; ++rt) {
        float v = l_acc[rt];
        v += __shfl_xor(v, 16);
        v += __shfl_xor(v, 32);
        if (lane < 16) lbuf[(w * 4 + rt) * 16 + lane] = v;
    }
    __syncthreads();
    // this thread's epilogue rows are r = 16w + l15 (rt = w)
    const float linv = 1.f / (lbuf[(0 + w) * 16 + l15] + lbuf[(4 + w) * 16 + l15] +
                              lbuf[(8 + w) * 16 + l15] + lbuf[(12 + w) * 16 + l15]);
    const float gl = gptr[0] * linv;

    // cross-wave O reduction in 8 cvt chunks; Obuf aliases Vls[0]
    f32x4* Obuf = (f32x4*)&Vls[0][0];
#pragma unroll
    for (int cvt = 0; cvt < 8; ++cvt) {
        __syncthreads();
#pragma unroll
        for (int rt = 0; rt < 4; ++rt)
            Obuf[(w * 64 + lane) * 5 + rt] = acc[cvt][rt];
        __syncthreads();
        f32x4 o = Obuf[lane * 5 + w];
        o += Obuf[(64 + lane) * 5 + w];
        o += Obuf[(128 + lane) * 5 + w];
        o += Obuf[(192 + lane) * 5 + w];
        // cv = 128cvh + 16cvt + 4q + reg -> c = 32cvh + 4cvt + q, d = reg
        size_t addr = ((size_t)(b * CH + 32 * cvh + 4 * cvt + q) * NN
                       + (r0 + 16 * w + l15)) * 4;
        float4 xr = *(const float4*)(x3d + addr);
        float4 res;
        res.x = fmaf(gl, o[0], xr.x);
        res.y = fmaf(gl, o[1], xr.y);
        res.z = fmaf(gl, o[2], xr.z);
        res.w = fmaf(gl, o[3], xr.w);
        *(float4*)(out + addr) = res;
    }
}

extern "C" void kernel_launch(void* const* d_in, const int* in_sizes, int n_in,
                              void* d_out, int out_size, void* d_ws, size_t ws_size,
                              hipStream_t stream)
{
    const float* x2d = (const float*)d_in[0];
    const float* x3d = (const float*)d_in[1];
    const float* Wq  = (const float*)d_in[2];
    const float* bq  = (const float*)d_in[3];
    const float* Wk  = (const float*)d_in[4];
    const float* bk  = (const float*)d_in[5];
    const float* Wv  = (const float*)d_in[6];
    const float* bv  = (const float*)d_in[7];
    const float* gma = (const float*)d_in[8];

    ushort* wsb = (ushort*)d_ws;

    qkv_kernel<<<1024, 256, 0, stream>>>(x2d, Wq, bq, Wk, bk, Wv, bv,
                                         wsb + QB_OFF, wsb + KB_OFF, wsb + VT_OFF);
    flash_kernel<<<512, 256, 0, stream>>>(wsb + QB_OFF, wsb + KB_OFF, wsb + VT_OFF,
                                          x3d, gma, (float*)d_out);
}